// Round 23
// baseline (496.059 us; speedup 1.0000x reference)
//
#include <hip/hip_runtime.h>
#include <hip/hip_bf16.h>

typedef __attribute__((ext_vector_type(8))) short short8;
typedef __attribute__((ext_vector_type(4))) float f32x4;
typedef __attribute__((ext_vector_type(4))) unsigned u32x4;
typedef unsigned long long u64;

#define T_STEPS 2048
#define HDIM 512
#define SLICE_T (64 * 512)      // elems per time slice
#define NGROUP 8                // batch groups (8 rows each)
#define NSLICE 16               // col slices (32 cols each)
#define CAN_OFF 0               // canaries: [128] 128B lines (16 KB)
#define COLSUM_OFF 16384        // colsum f32[512]
#define FPOS_OFF 32768          // fpos u64[2048] (16 KB): row stays +1
#define FNEG_OFF 49152          // fneg u64[2048] (16 KB): row stays -1
#define WHI_OFF 65536           // packed Wx hi-plane, frag-ordered (512 KB)
#define WLO_OFF (65536 + 524288)            // lo-plane (512 KB)
#define RING_OFF 65536          // ring [2][64][512] u32 (256 KB) — ALIASES
                                // WHI region; safe: scan runs after xproj
#define SPIN_CAP 200000
#define SAT_MARGIN 9.2f         // tanhf==+-1.0f for |x|>9.011; margin >> skew

#define MFMA16 __builtin_amdgcn_mfma_f32_16x16x32_bf16
#define ALOAD(p)   __hip_atomic_load((p), __ATOMIC_RELAXED, __HIP_MEMORY_SCOPE_AGENT)
#define ASWAP(p,v) (void)__hip_atomic_exchange((p), (v), __ATOMIC_RELAXED, __HIP_MEMORY_SCOPE_AGENT)

static __device__ __forceinline__ short f2bf(float f) {
    __hip_bfloat16 h = __float2bfloat16(f);
    return __builtin_bit_cast(short, h);
}
static __device__ __forceinline__ float bf2f(short s) {
    unsigned u = ((unsigned)(unsigned short)s) << 16;
    return __builtin_bit_cast(float, u);
}
static __device__ __forceinline__ unsigned packsplit(float f) {
    short hi = f2bf(f);
    short lo = f2bf(f - bf2f(hi));
    return (unsigned)(unsigned short)hi | ((unsigned)(unsigned short)lo << 16);
}
static __device__ __forceinline__ unsigned pk2(short a, short b) {
    return (unsigned)(unsigned short)a | ((unsigned)(unsigned short)b << 16);
}
// pack TOP-16-bits (truncated bf16) of two f32 into one u32 — 1 instruction
static __device__ __forceinline__ unsigned pkhi2f(float a, float b) {
    return __builtin_amdgcn_perm(__builtin_bit_cast(unsigned, b),
                                 __builtin_bit_cast(unsigned, a), 0x07060302u);
}
// f32 with mantissa truncated to bf16 (bitwise AND)
static __device__ __forceinline__ float ftrunc16(float f) {
    return __builtin_bit_cast(float, __builtin_bit_cast(unsigned, f) & 0xFFFF0000u);
}
static __device__ __forceinline__ void unpack2w(unsigned p0, unsigned p1,
                                                unsigned& hw, unsigned& lw) {
    hw = __builtin_amdgcn_perm(p1, p0, 0x05040100u);
    lw = __builtin_amdgcn_perm(p1, p0, 0x07060302u);
}
union S8U { short8 s8; unsigned u[4]; };
static __device__ __forceinline__ void build8v(u32x4 a, u32x4 b, short8& hi, short8& lo) {
    S8U H, L;
    unpack2w(a[0], a[1], H.u[0], L.u[0]);
    unpack2w(a[2], a[3], H.u[1], L.u[1]);
    unpack2w(b[0], b[1], H.u[2], L.u[2]);
    unpack2w(b[2], b[3], H.u[3], L.u[3]);
    hi = H.s8; lo = L.s8;
}
static __device__ __forceinline__ void split8v(f32x4 u, f32x4 v, short8& hi, short8& lo) {
#pragma unroll
    for (int j = 0; j < 4; ++j) { short h = f2bf(u[j]); hi[j] = h; lo[j] = f2bf(u[j] - bf2f(h)); }
#pragma unroll
    for (int j = 0; j < 4; ++j) { short h = f2bf(v[j]); hi[4+j] = h; lo[4+j] = f2bf(v[j] - bf2f(h)); }
}
static __device__ __forceinline__ float fast_tanh(float x) {
    const float xc = fminf(15.0f, fmaxf(-15.0f, x));
    const float e = __expf(2.0f * xc);
    return (e - 1.0f) / (e + 1.0f);
}

// ------- Phase 0a: colsum_c = sum_k Wh[k][c] ------------------------------
__global__ __launch_bounds__(512, 1) void rnn_colsum(
    const float* __restrict__ weight, float* __restrict__ colsum)
{
    const int c = threadIdx.x;
    float s = 0.f;
    for (int k = 0; k < HDIM; ++k) s += weight[(size_t)(HDIM + k) * HDIM + c];
    colsum[c] = s;
}

// ------- Phase 0b: pre-pack Wx, FRAGMENT-ORDERED hi/lo planes -------------
__global__ __launch_bounds__(512, 1) void rnn_packw(
    const float* __restrict__ weight, unsigned* __restrict__ whi,
    unsigned* __restrict__ wlo)
{
    const int idx = blockIdx.x * 512 + threadIdx.x;   // k2*512 + c order
    const int k2 = idx >> 9, c = idx & 511;
    const float w0 = weight[(size_t)(2 * k2) * HDIM + c];
    const float w1 = weight[(size_t)(2 * k2 + 1) * HDIM + c];
    const short h0 = f2bf(w0), h1 = f2bf(w1);
    const int dst = ((k2 >> 4) * 512 + c) * 16 + (k2 & 15);
    whi[dst] = pk2(h0, h1);
    wlo[dst] = pk2(f2bf(w0 - bf2f(h0)), f2bf(w1 - bf2f(h1)));
}

// ------- Phase 1: xp(t) = input[t] @ Wx + bias -> out[t+1], flags fused ---
// 512-thr blocks, 2x4 wave grid: wave (wr,wc) owns 2 row-subtiles (32
// rows) x 2 col-subtiles (32 cols). Halves the 8x-redundant LDS A-reads
// of R22 (each wave read the FULL quarter); MFMA count unchanged ->
// LDS pipe off the critical path. B-frags loaded per-c2 (small live
// range, ~100 VGPR total < 128 cap). Accumulation order per column
// unchanged -> xp bit-identical -> sprint/flags preserved.
__global__ __launch_bounds__(512, 1) void rnn_xproj(
    const float* __restrict__ input, const unsigned* __restrict__ whi,
    const unsigned* __restrict__ wlo, const float* __restrict__ bias,
    const float* __restrict__ colsum, float* __restrict__ out,
    unsigned* __restrict__ fpos32, unsigned* __restrict__ fneg32)
{
    __shared__ unsigned ahi[64 * 64];   // one kq quarter [row][k2l], 16 KB
    __shared__ unsigned alo[64 * 64];
    __shared__ unsigned sf[4];

    const int tid = threadIdx.x, lane = tid & 63, wv = tid >> 6;  // wv 0..7
    const int wr = wv >> 2, wc = wv & 3;     // 2x4 wave grid
    const int b = blockIdx.x, xcd = b & 7, rest = b >> 3;
    const int t = xcd * 256 + (rest >> 2), quarter = rest & 3;
    const int r16 = lane & 15, kg = lane >> 4;
    const int colbase = quarter * 128 + wc * 32;   // 2 cs subtiles

    if (tid < 4) sf[tid] = 0u;

    f32x4 acc[2][2][3];   // [cs][mt][chain]
#pragma unroll
    for (int cs = 0; cs < 2; ++cs) {
        const float bv = bias[colbase + cs * 16 + r16];
#pragma unroll
        for (int mt = 0; mt < 2; ++mt) {
            acc[cs][mt][0] = (f32x4){bv, bv, bv, bv};
            acc[cs][mt][1] = (f32x4){0, 0, 0, 0};
            acc[cs][mt][2] = (f32x4){0, 0, 0, 0};
        }
    }
    const float* ibase = input + (size_t)t * SLICE_T;

#pragma unroll
    for (int kq = 0; kq < 4; ++kq) {
        __syncthreads();   // previous quarter's reads complete
        // ---- stage quarter: trunc-pack, 3 ops/elem (proven R22) ----
#pragma unroll
        for (int i = 0; i < 2; ++i) {
            const int flat = tid + i * 512;          // 0..1023 chunks
            const int row = flat >> 4, g4 = flat & 15;
            const float* p = ibase + row * HDIM + kq * 128 + g4 * 8;
            f32x4 a = *(const f32x4*)p;
            f32x4 c4 = *(const f32x4*)(p + 4);
            u32x4 H = {pkhi2f(a[0], a[1]),  pkhi2f(a[2], a[3]),
                       pkhi2f(c4[0], c4[1]), pkhi2f(c4[2], c4[3])};
            const float d0 = a[0] - ftrunc16(a[0]),  d1 = a[1] - ftrunc16(a[1]);
            const float d2 = a[2] - ftrunc16(a[2]),  d3 = a[3] - ftrunc16(a[3]);
            const float d4 = c4[0] - ftrunc16(c4[0]), d5 = c4[1] - ftrunc16(c4[1]);
            const float d6 = c4[2] - ftrunc16(c4[2]), d7 = c4[3] - ftrunc16(c4[3]);
            u32x4 L = {pkhi2f(d0, d1), pkhi2f(d2, d3),
                       pkhi2f(d4, d5), pkhi2f(d6, d7)};
            const int dst = row * 64 + ((g4 * 4) ^ ((row & 7) << 2));
            *(u32x4*)&ahi[dst] = H;
            *(u32x4*)&alo[dst] = L;
        }
        __syncthreads();
        // ---- inner: per c2, load B (2 cs), then 2 mt x {A-read, 6 MFMA} ----
#pragma unroll
        for (int c2 = 0; c2 < 4; ++c2) {
            const int kb = kq * 4 + c2;
            short8 bh[2], bl[2];
#pragma unroll
            for (int cs = 0; cs < 2; ++cs) {
                const int base = (kb * 512 + colbase + cs * 16 + r16) * 16 + kg * 4;
                bh[cs] = __builtin_bit_cast(short8, *(const u32x4*)&whi[base]);
                bl[cs] = __builtin_bit_cast(short8, *(const u32x4*)&wlo[base]);
            }
            const int cb = c2 * 16 + kg * 4;
#pragma unroll
            for (int mt = 0; mt < 2; ++mt) {
                const int row = wr * 32 + mt * 16 + r16;
                const int ad = row * 64 + (cb ^ ((row & 7) << 2));
                short8 AH = __builtin_bit_cast(short8, *(const u32x4*)&ahi[ad]);
                short8 AL = __builtin_bit_cast(short8, *(const u32x4*)&alo[ad]);
#pragma unroll
                for (int cs = 0; cs < 2; ++cs) {
                    acc[cs][mt][0] = MFMA16(AH, bh[cs], acc[cs][mt][0], 0, 0, 0);
                    acc[cs][mt][1] = MFMA16(AL, bh[cs], acc[cs][mt][1], 0, 0, 0);
                    acc[cs][mt][2] = MFMA16(AH, bl[cs], acc[cs][mt][2], 0, 0, 0);
                }
            }
        }
    }

    // ---- epilogue: store xp + fused sign-persistence flags ----
    unsigned fP0 = 0, fP1 = 0, fN0 = 0, fN1 = 0;
    float* ob = out + (size_t)(t + 1) * SLICE_T;
#pragma unroll
    for (int cs = 0; cs < 2; ++cs) {
        const int col = colbase + cs * 16 + r16;
        const float cscol = colsum[col];
#pragma unroll
        for (int mt = 0; mt < 2; ++mt)
#pragma unroll
            for (int r = 0; r < 4; ++r) {
                const int row = wr * 32 + mt * 16 + kg * 4 + r;
                const float v = acc[cs][mt][0][r] + acc[cs][mt][1][r] + acc[cs][mt][2][r];
                ob[(size_t)row * HDIM + col] = v;
                const unsigned bit = 1u << (row & 31);
                if (v + cscol <= SAT_MARGIN)  { if (row < 32) fP0 |= bit; else fP1 |= bit; }
                if (v - cscol >= -SAT_MARGIN) { if (row < 32) fN0 |= bit; else fN1 |= bit; }
            }
    }
#pragma unroll
    for (int off = 32; off; off >>= 1) {
        fP0 |= __shfl_xor(fP0, off); fP1 |= __shfl_xor(fP1, off);
        fN0 |= __shfl_xor(fN0, off); fN1 |= __shfl_xor(fN1, off);
    }
    if (lane == 0) {
        atomicOr(&sf[0], fP0); atomicOr(&sf[1], fP1);
        atomicOr(&sf[2], fN0); atomicOr(&sf[3], fN1);
    }
    __syncthreads();
    if (tid < 2) atomicAnd(&fpos32[t * 2 + tid], ~sf[tid]);
    else if (tid < 4) atomicAnd(&fneg32[t * 2 + (tid - 2)], ~sf[tid]);
}

// ------- Phase 2: persistent scan + per-row-sign sprint, 64-step batched --
// (proven R18/R22, byte-identical)
__global__ __launch_bounds__(128, 1) void rnn_scan(
    const float* __restrict__ weight, const float* __restrict__ init_h,
    const float* __restrict__ colsum, float* __restrict__ out,
    unsigned char* __restrict__ ws)
{
    __shared__ u32x4 whfA[16][2][64];
    __shared__ u32x4 whfB[16][2][64];
    unsigned* canary = (unsigned*)(ws + CAN_OFF);
    const u64* fpos = (const u64*)(ws + FPOS_OFF);
    const u64* fneg = (const u64*)(ws + FNEG_OFF);
    unsigned* ring = (unsigned*)(ws + RING_OFF);

    const int tid = threadIdx.x, lane = tid & 63, wv = tid >> 6;
    const int g = blockIdx.x & 7, s = blockIdx.x >> 3;
    const int r16 = lane & 15, kg = lane >> 4, koff = kg * 8;
    const int gcol = s * 32 + wv * 16 + r16;
    const int brow = g * 8 + (r16 & 7);

#pragma unroll
    for (int c = 0; c < 16; ++c) {
        unsigned p[8];
#pragma unroll
        for (int j = 0; j < 8; ++j)
            p[j] = packsplit(weight[(size_t)(HDIM + c * 32 + koff + j) * HDIM + gcol]);
        whfA[c][wv][lane] = (u32x4){p[0], p[1], p[2], p[3]};
        whfB[c][wv][lane] = (u32x4){p[4], p[5], p[6], p[7]};
    }
    for (int f = tid; f < 8 * 32; f += 128) {
        const int rr = f >> 5, cc = f & 31;
        out[(size_t)(g * 8 + rr) * HDIM + s * 32 + cc] = init_h[s * 32 + cc];
    }
    __syncthreads();

    int sprint = 0;
    unsigned smask = 0;   // bit b: row g*8+b is -1 (else +1); wave-uniform
    for (int t = 0; t < T_STEPS; ++t) {
        const bool has_next = (t + 1 < T_STEPS);

        if (sprint) {
            const unsigned pm = (~smask) & 0xFFu;
            if (t + 64 <= T_STEPS) {
                int pass = 1;
                {
                    const u64 fp = fpos[t + lane], fn = fneg[t + lane];
                    const unsigned fpg = (unsigned)((fp >> (g * 8)) & 0xFFull);
                    const unsigned fng = (unsigned)((fn >> (g * 8)) & 0xFFull);
                    pass = (((fpg & pm) == pm) && ((fng & smask) == smask)) ? 1 : 0;
                }
                if (__all(pass)) {
                    float* base = out + (size_t)(g * 8) * HDIM + s * 32;
#pragma unroll
                    for (int w = 0; w < 32; ++w) {
                        const int idx = w * 128 + tid;        // 0..4095
                        const int t2 = t + (idx >> 6);
                        const int v4i = idx & 63;
                        const int row = v4i >> 3, c4 = v4i & 7;
                        const float vv = ((smask >> row) & 1u) ? -1.0f : 1.0f;
                        const f32x4 vvec = {vv, vv, vv, vv};
                        __builtin_nontemporal_store(
                            vvec, (f32x4*)(base + (size_t)(t2 + 1) * SLICE_T
                                                + (size_t)row * HDIM + c4 * 4));
                    }
                    t += 63;
                    continue;
                }
            }
            const unsigned fpg = (unsigned)((fpos[t] >> (g * 8)) & 0xFFull);
            const unsigned fng = (unsigned)((fneg[t] >> (g * 8)) & 0xFFull);
            if (((fpg & pm) == pm) && ((fng & smask) == smask)) {
                float* ob = out + (size_t)(t + 1) * SLICE_T + (size_t)(g * 8) * HDIM + s * 32;
                for (int i = tid; i < 8 * 32; i += 128) {
                    const int r = i >> 5;
                    const float v = ((smask >> r) & 1u) ? -1.0f : 1.0f;
                    __builtin_nontemporal_store(v, ob + (size_t)r * HDIM + (i & 31));
                }
                continue;
            }
            const float* xpp = out + (size_t)(t + 1) * SLICE_T
                                   + (size_t)(g * 8 + (kg & 1) * 4) * HDIM + gcol;
            const float cs = colsum[gcol];
            float hn[4];
#pragma unroll
            for (int r = 0; r < 4; ++r) {
                const int rr = (kg & 1) * 4 + r;
                const float sg_ = ((smask >> rr) & 1u) ? -1.0f : 1.0f;
                hn[r] = fast_tanh(xpp[r * HDIM] + sg_ * cs);
            }
            if (kg < 2 && has_next) {
                unsigned* wsl = ring + ((t + 1) & 1) * SLICE_T
                                     + (size_t)(g * 8 + kg * 4) * HDIM + gcol;
#pragma unroll
                for (int r = 0; r < 4; ++r)
                    ASWAP(&wsl[r * HDIM], packsplit(hn[r]));
            }
            asm volatile("s_waitcnt vmcnt(0)" ::: "memory");
            __syncthreads();
            if (tid == 0 && has_next)
                ASWAP(&canary[(g * NSLICE + s) * 32], (unsigned)(t + 1));
            if (kg < 2) {
                float* op = out + (size_t)(t + 1) * SLICE_T
                                + (size_t)(g * 8 + kg * 4) * HDIM + gcol;
#pragma unroll
                for (int r = 0; r < 4; ++r)
                    __builtin_nontemporal_store(hn[r], op + (size_t)r * HDIM);
            }
            sprint = 0;
            continue;
        }

        const float* xpp = out + (size_t)(t + 1) * SLICE_T
                               + (size_t)(g * 8 + (kg & 1) * 4) * HDIM + gcol;
        const float xp0 = xpp[0 * HDIM], xp1 = xpp[1 * HDIM];
        const float xp2 = xpp[2 * HDIM], xp3 = xpp[3 * HDIM];

        f32x4 aA = {0, 0, 0, 0}, aB = {0, 0, 0, 0}, aC = {0, 0, 0, 0};

        if (t == 0) {
#pragma unroll
            for (int c = 0; c < 16; ++c) {
                f32x4 u = *(const f32x4*)(init_h + c * 32 + koff);
                f32x4 v = *(const f32x4*)(init_h + c * 32 + koff + 4);
                short8 ahi_, alo_; split8v(u, v, ahi_, alo_);
                short8 bhi, blo; build8v(whfA[c][wv][lane], whfB[c][wv][lane], bhi, blo);
                aA = MFMA16(ahi_, bhi, aA, 0, 0, 0);
                aB = MFMA16(alo_, bhi, aB, 0, 0, 0);
                aC = MFMA16(ahi_, blo, aC, 0, 0, 0);
            }
        } else {
            int to = 0;
            if (wv == 0) {
                unsigned it = 0;
                for (;;) {
                    unsigned cv = 0xffffffffu;
                    if (lane < NSLICE) cv = ALOAD(&canary[(g * NSLICE + lane) * 32]);
                    if (__all((int)(cv >= (unsigned)t))) break;
                    if (++it > SPIN_CAP) { to = 1; break; }
                }
            }
            if (__syncthreads_count(to)) return;

            const unsigned* rb = ring + (t & 1) * SLICE_T + brow * HDIM;
            unsigned long long q[16][4];
#pragma unroll
            for (int c = 0; c < 16; ++c) {
                const unsigned* p = rb + c * 32 + koff;
                q[c][0] = ALOAD((const unsigned long long*)(p + 0));
                q[c][1] = ALOAD((const unsigned long long*)(p + 2));
                q[c][2] = ALOAD((const unsigned long long*)(p + 4));
                q[c][3] = ALOAD((const unsigned long long*)(p + 6));
            }
            const unsigned long long P2 = 0x00003F8000003F80ull;  // +1,+1
            const unsigned long long N2 = 0x0000BF800000BF80ull;  // -1,-1
            unsigned long long dp = 0, dn = 0;
#pragma unroll
            for (int c = 0; c < 16; ++c) {
                dp |= (q[c][0] ^ P2) | (q[c][1] ^ P2) | (q[c][2] ^ P2) | (q[c][3] ^ P2);
                dn |= (q[c][0] ^ N2) | (q[c][1] ^ N2) | (q[c][2] ^ N2) | (q[c][3] ^ N2);
            }
            const unsigned code = (dp == 0ull) ? 0u : ((dn == 0ull) ? 1u : 2u);
            const unsigned long long balneg = __ballot((int)(code == 1u));
            const unsigned long long balbad = __ballot((int)(code == 2u));
            const unsigned my = (unsigned)((balneg >> (lane & 7)) & 1ull);
            const bool entry = (balbad == 0ull) && __all((int)(code == my));
            if (entry) {
                const unsigned sm = (unsigned)(balneg & 0xFFull);
                const unsigned fpg = (unsigned)((fpos[t] >> (g * 8)) & 0xFFull);
                const unsigned fng = (unsigned)((fneg[t] >> (g * 8)) & 0xFFull);
                const unsigned pm = (~sm) & 0xFFu;
                if (((fpg & pm) == pm) && ((fng & sm) == sm)) {
                    float* ob = out + (size_t)(t + 1) * SLICE_T + (size_t)(g * 8) * HDIM + s * 32;
                    for (int i = tid; i < 8 * 32; i += 128) {
                        const int r = i >> 5;
                        const float v = ((sm >> r) & 1u) ? -1.0f : 1.0f;
                        __builtin_nontemporal_store(v, ob + (size_t)r * HDIM + (i & 31));
                    }
                    sprint = 1; smask = sm;
                    continue;
                }
            }
#pragma unroll
            for (int c = 0; c < 16; ++c) {
                S8U hh, hl;
                unpack2w((unsigned)q[c][0], (unsigned)(q[c][0] >> 32), hh.u[0], hl.u[0]);
                unpack2w((unsigned)q[c][1], (unsigned)(q[c][1] >> 32), hh.u[1], hl.u[1]);
                unpack2w((unsigned)q[c][2], (unsigned)(q[c][2] >> 32), hh.u[2], hl.u[2]);
                unpack2w((unsigned)q[c][3], (unsigned)(q[c][3] >> 32), hh.u[3], hl.u[3]);
                short8 bhi, blo; build8v(whfA[c][wv][lane], whfB[c][wv][lane], bhi, blo);
                aA = MFMA16(hh.s8, bhi, aA, 0, 0, 0);
                aB = MFMA16(hl.s8, bhi, aB, 0, 0, 0);
                aC = MFMA16(hh.s8, blo, aC, 0, 0, 0);
            }
        }

        const float hn0 = fast_tanh(aA[0] + aB[0] + aC[0] + xp0);
        const float hn1 = fast_tanh(aA[1] + aB[1] + aC[1] + xp1);
        const float hn2 = fast_tanh(aA[2] + aB[2] + aC[2] + xp2);
        const float hn3 = fast_tanh(aA[3] + aB[3] + aC[3] + xp3);

        if (kg < 2 && has_next) {
            unsigned* wsl = ring + ((t + 1) & 1) * SLICE_T
                                 + (size_t)(g * 8 + kg * 4) * HDIM + gcol;
            ASWAP(&wsl[0 * HDIM], packsplit(hn0));
            ASWAP(&wsl[1 * HDIM], packsplit(hn1));
            ASWAP(&wsl[2 * HDIM], packsplit(hn2));
            ASWAP(&wsl[3 * HDIM], packsplit(hn3));
        }
        asm volatile("s_waitcnt vmcnt(0)" ::: "memory");
        __syncthreads();
        if (tid == 0 && has_next)
            ASWAP(&canary[(g * NSLICE + s) * 32], (unsigned)(t + 1));

        if (kg < 2) {
            float* op = out + (size_t)(t + 1) * SLICE_T
                            + (size_t)(g * 8 + kg * 4) * HDIM + gcol;
            __builtin_nontemporal_store(hn0, op + 0 * HDIM);
            __builtin_nontemporal_store(hn1, op + 1 * HDIM);
            __builtin_nontemporal_store(hn2, op + 2 * HDIM);
            __builtin_nontemporal_store(hn3, op + 3 * HDIM);
        }
    }
}

extern "C" void kernel_launch(void* const* d_in, const int* in_sizes, int n_in,
                              void* d_out, int out_size, void* d_ws, size_t ws_size,
                              hipStream_t stream) {
    const float* input  = (const float*)d_in[0];
    const float* weight = (const float*)d_in[1];
    const float* biasp  = (const float*)d_in[2];
    const float* inith  = (const float*)d_in[3];
    float* out = (float*)d_out;
    unsigned char* ws = (unsigned char*)d_ws;

    hipMemsetAsync(ws + CAN_OFF, 0, 16384, stream);
    hipMemsetAsync(ws + FPOS_OFF, 0xFF, 32768, stream);

    rnn_colsum<<<dim3(1), dim3(512), 0, stream>>>(weight, (float*)(ws + COLSUM_OFF));
    rnn_packw<<<dim3(256), dim3(512), 0, stream>>>(
        weight, (unsigned*)(ws + WHI_OFF), (unsigned*)(ws + WLO_OFF));
    rnn_xproj<<<dim3(T_STEPS * 4), dim3(512), 0, stream>>>(
        input, (const unsigned*)(ws + WHI_OFF), (const unsigned*)(ws + WLO_OFF),
        biasp, (const float*)(ws + COLSUM_OFF), out,
        (unsigned*)(ws + FPOS_OFF), (unsigned*)(ws + FNEG_OFF));
    rnn_scan<<<dim3(NGROUP * NSLICE), dim3(128), 0, stream>>>(
        weight, inith, (const float*)(ws + COLSUM_OFF), out, ws);
}

// Round 24
// 415.753 us; speedup vs baseline: 1.1932x; 1.1932x over previous
//
#include <hip/hip_runtime.h>
#include <hip/hip_bf16.h>

typedef __attribute__((ext_vector_type(8))) short short8;
typedef __attribute__((ext_vector_type(4))) float f32x4;
typedef __attribute__((ext_vector_type(4))) unsigned u32x4;
typedef unsigned long long u64;

#define T_STEPS 2048
#define HDIM 512
#define SLICE_T (64 * 512)      // elems per time slice
#define NGROUP 8                // batch groups (8 rows each)
#define NSLICE 16               // col slices (32 cols each)
#define CAN_OFF 0               // canaries: [128] 128B lines (16 KB)
#define COLSUM_OFF 16384        // colsum f32[512]
#define FPOS_OFF 32768          // fpos u64[2048] (16 KB): row stays +1
#define FNEG_OFF 49152          // fneg u64[2048] (16 KB): row stays -1
#define WHI_OFF 65536           // packed Wx hi-plane, frag-ordered (512 KB)
#define WLO_OFF (65536 + 524288)            // lo-plane (512 KB)
#define RING_OFF 65536          // ring [2][64][512] u32 (256 KB) — ALIASES
                                // WHI region; safe: scan runs after xproj
#define SPIN_CAP 200000
#define SAT_MARGIN 9.2f         // tanhf==+-1.0f for |x|>9.011; margin >> skew

#define MFMA16 __builtin_amdgcn_mfma_f32_16x16x32_bf16
#define ALOAD(p)   __hip_atomic_load((p), __ATOMIC_RELAXED, __HIP_MEMORY_SCOPE_AGENT)
#define ASWAP(p,v) (void)__hip_atomic_exchange((p), (v), __ATOMIC_RELAXED, __HIP_MEMORY_SCOPE_AGENT)

static __device__ __forceinline__ short f2bf(float f) {
    __hip_bfloat16 h = __float2bfloat16(f);
    return __builtin_bit_cast(short, h);
}
static __device__ __forceinline__ float bf2f(short s) {
    unsigned u = ((unsigned)(unsigned short)s) << 16;
    return __builtin_bit_cast(float, u);
}
static __device__ __forceinline__ unsigned packsplit(float f) {
    short hi = f2bf(f);
    short lo = f2bf(f - bf2f(hi));
    return (unsigned)(unsigned short)hi | ((unsigned)(unsigned short)lo << 16);
}
static __device__ __forceinline__ unsigned pk2(short a, short b) {
    return (unsigned)(unsigned short)a | ((unsigned)(unsigned short)b << 16);
}
// pack TOP-16-bits (truncated bf16) of two f32 into one u32 — 1 instruction
static __device__ __forceinline__ unsigned pkhi2f(float a, float b) {
    return __builtin_amdgcn_perm(__builtin_bit_cast(unsigned, b),
                                 __builtin_bit_cast(unsigned, a), 0x07060302u);
}
// f32 with mantissa truncated to bf16 (bitwise AND)
static __device__ __forceinline__ float ftrunc16(float f) {
    return __builtin_bit_cast(float, __builtin_bit_cast(unsigned, f) & 0xFFFF0000u);
}
static __device__ __forceinline__ void unpack2w(unsigned p0, unsigned p1,
                                                unsigned& hw, unsigned& lw) {
    hw = __builtin_amdgcn_perm(p1, p0, 0x05040100u);
    lw = __builtin_amdgcn_perm(p1, p0, 0x07060302u);
}
union S8U { short8 s8; unsigned u[4]; };
static __device__ __forceinline__ void build8v(u32x4 a, u32x4 b, short8& hi, short8& lo) {
    S8U H, L;
    unpack2w(a[0], a[1], H.u[0], L.u[0]);
    unpack2w(a[2], a[3], H.u[1], L.u[1]);
    unpack2w(b[0], b[1], H.u[2], L.u[2]);
    unpack2w(b[2], b[3], H.u[3], L.u[3]);
    hi = H.s8; lo = L.s8;
}
static __device__ __forceinline__ void split8v(f32x4 u, f32x4 v, short8& hi, short8& lo) {
#pragma unroll
    for (int j = 0; j < 4; ++j) { short h = f2bf(u[j]); hi[j] = h; lo[j] = f2bf(u[j] - bf2f(h)); }
#pragma unroll
    for (int j = 0; j < 4; ++j) { short h = f2bf(v[j]); hi[4+j] = h; lo[4+j] = f2bf(v[j] - bf2f(h)); }
}
static __device__ __forceinline__ float fast_tanh(float x) {
    const float xc = fminf(15.0f, fmaxf(-15.0f, x));
    const float e = __expf(2.0f * xc);
    return (e - 1.0f) / (e + 1.0f);
}

// ------- Phase 0a: colsum_c = sum_k Wh[k][c] ------------------------------
__global__ __launch_bounds__(512, 1) void rnn_colsum(
    const float* __restrict__ weight, float* __restrict__ colsum)
{
    const int c = threadIdx.x;
    float s = 0.f;
    for (int k = 0; k < HDIM; ++k) s += weight[(size_t)(HDIM + k) * HDIM + c];
    colsum[c] = s;
}

// ------- Phase 0b: pre-pack Wx, FRAGMENT-ORDERED hi/lo planes -------------
__global__ __launch_bounds__(512, 1) void rnn_packw(
    const float* __restrict__ weight, unsigned* __restrict__ whi,
    unsigned* __restrict__ wlo)
{
    const int idx = blockIdx.x * 512 + threadIdx.x;   // k2*512 + c order
    const int k2 = idx >> 9, c = idx & 511;
    const float w0 = weight[(size_t)(2 * k2) * HDIM + c];
    const float w1 = weight[(size_t)(2 * k2 + 1) * HDIM + c];
    const short h0 = f2bf(w0), h1 = f2bf(w1);
    const int dst = ((k2 >> 4) * 512 + c) * 16 + (k2 & 15);
    whi[dst] = pk2(h0, h1);
    wlo[dst] = pk2(f2bf(w0 - bf2f(h0)), f2bf(w1 - bf2f(h1)));
}

// ------- Phase 1: xp(t) = input[t] @ Wx + bias -> out[t+1], flags fused ---
// R22's proven structure (1x8 wave grid, wave owns 16 cols, 4 blocks/t,
// VGPR 52) + T14 async-stage split: quarter kq+1's global loads are
// ISSUED before kq's MFMA block and land during it (~960 cyc of MFMA
// covers the ~500-900 cyc HBM/L2 latency); conversion happens next
// iteration from registers. Barrier count unchanged. Accumulation order
// unchanged -> xp bit-identical -> sprint/flags preserved.
__global__ __launch_bounds__(512, 1) void rnn_xproj(
    const float* __restrict__ input, const unsigned* __restrict__ whi,
    const unsigned* __restrict__ wlo, const float* __restrict__ bias,
    const float* __restrict__ colsum, float* __restrict__ out,
    unsigned* __restrict__ fpos32, unsigned* __restrict__ fneg32)
{
    __shared__ unsigned ahi[64 * 64];   // one kq quarter [row][k2l], 16 KB
    __shared__ unsigned alo[64 * 64];
    __shared__ unsigned sf[4];

    const int tid = threadIdx.x, lane = tid & 63, wv = tid >> 6;  // wv 0..7
    const int b = blockIdx.x, xcd = b & 7, rest = b >> 3;
    const int t = xcd * 256 + (rest >> 2), quarter = rest & 3;
    const int r16 = lane & 15, kg = lane >> 4;
    const int col = quarter * 128 + wv * 16 + r16;   // this lane's column

    if (tid < 4) sf[tid] = 0u;

    const float bv = bias[col];
    f32x4 acc[4][3];
#pragma unroll
    for (int mt = 0; mt < 4; ++mt) {
        acc[mt][0] = (f32x4){bv, bv, bv, bv};
        acc[mt][1] = (f32x4){0, 0, 0, 0};
        acc[mt][2] = (f32x4){0, 0, 0, 0};
    }
    const float* ibase = input + (size_t)t * SLICE_T;
    const int row_s0 = (tid + 0) >> 4,   g4_s0 = (tid + 0) & 15;
    const int row_s1 = (tid + 512) >> 4, g4_s1 = (tid + 512) & 15;

    // ---- prologue: prefetch quarter 0 into registers ----
    f32x4 pa0, pc0, pa1, pc1;
    {
        const float* p0 = ibase + row_s0 * HDIM + g4_s0 * 8;
        const float* p1 = ibase + row_s1 * HDIM + g4_s1 * 8;
        pa0 = *(const f32x4*)p0; pc0 = *(const f32x4*)(p0 + 4);
        pa1 = *(const f32x4*)p1; pc1 = *(const f32x4*)(p1 + 4);
    }

#pragma unroll
    for (int kq = 0; kq < 4; ++kq) {
        // ---- convert + write staged quarter (from registers) ----
        {
            u32x4 H0 = {pkhi2f(pa0[0], pa0[1]),  pkhi2f(pa0[2], pa0[3]),
                        pkhi2f(pc0[0], pc0[1]),  pkhi2f(pc0[2], pc0[3])};
            u32x4 L0 = {pkhi2f(pa0[0] - ftrunc16(pa0[0]), pa0[1] - ftrunc16(pa0[1])),
                        pkhi2f(pa0[2] - ftrunc16(pa0[2]), pa0[3] - ftrunc16(pa0[3])),
                        pkhi2f(pc0[0] - ftrunc16(pc0[0]), pc0[1] - ftrunc16(pc0[1])),
                        pkhi2f(pc0[2] - ftrunc16(pc0[2]), pc0[3] - ftrunc16(pc0[3]))};
            const int dst0 = row_s0 * 64 + ((g4_s0 * 4) ^ ((row_s0 & 7) << 2));
            *(u32x4*)&ahi[dst0] = H0;
            *(u32x4*)&alo[dst0] = L0;
            u32x4 H1 = {pkhi2f(pa1[0], pa1[1]),  pkhi2f(pa1[2], pa1[3]),
                        pkhi2f(pc1[0], pc1[1]),  pkhi2f(pc1[2], pc1[3])};
            u32x4 L1 = {pkhi2f(pa1[0] - ftrunc16(pa1[0]), pa1[1] - ftrunc16(pa1[1])),
                        pkhi2f(pa1[2] - ftrunc16(pa1[2]), pa1[3] - ftrunc16(pa1[3])),
                        pkhi2f(pc1[0] - ftrunc16(pc1[0]), pc1[1] - ftrunc16(pc1[1])),
                        pkhi2f(pc1[2] - ftrunc16(pc1[2]), pc1[3] - ftrunc16(pc1[3]))};
            const int dst1 = row_s1 * 64 + ((g4_s1 * 4) ^ ((row_s1 & 7) << 2));
            *(u32x4*)&ahi[dst1] = H1;
            *(u32x4*)&alo[dst1] = L1;
        }
        __syncthreads();
        // ---- issue next quarter's global loads (land during MFMAs) ----
        if (kq < 3) {
            const float* p0 = ibase + row_s0 * HDIM + (kq + 1) * 128 + g4_s0 * 8;
            const float* p1 = ibase + row_s1 * HDIM + (kq + 1) * 128 + g4_s1 * 8;
            pa0 = *(const f32x4*)p0; pc0 = *(const f32x4*)(p0 + 4);
            pa1 = *(const f32x4*)p1; pc1 = *(const f32x4*)(p1 + 4);
        }
        // ---- B frags: contiguous 16B loads (proven R22) ----
        short8 bh[4], bl[4];
#pragma unroll
        for (int c2 = 0; c2 < 4; ++c2) {
            const int kb = kq * 4 + c2;
            const int base = (kb * 512 + col) * 16 + kg * 4;
            bh[c2] = __builtin_bit_cast(short8, *(const u32x4*)&whi[base]);
            bl[c2] = __builtin_bit_cast(short8, *(const u32x4*)&wlo[base]);
        }
        // ---- inner: 2x ds_read_b128 + 3 MFMA per A-frag ----
#pragma unroll
        for (int c2 = 0; c2 < 4; ++c2) {
            const int cb = c2 * 16 + kg * 4;
#pragma unroll
            for (int mt = 0; mt < 4; ++mt) {
                const int row = mt * 16 + r16;
                const int ad = row * 64 + (cb ^ ((row & 7) << 2));
                short8 AH = __builtin_bit_cast(short8, *(const u32x4*)&ahi[ad]);
                short8 AL = __builtin_bit_cast(short8, *(const u32x4*)&alo[ad]);
                acc[mt][0] = MFMA16(AH, bh[c2], acc[mt][0], 0, 0, 0);
                acc[mt][1] = MFMA16(AL, bh[c2], acc[mt][1], 0, 0, 0);
                acc[mt][2] = MFMA16(AH, bl[c2], acc[mt][2], 0, 0, 0);
            }
        }
        __syncthreads();   // LDS reads complete before next quarter's write
    }

    // ---- epilogue: store xp + fused sign-persistence flags ----
    const float cscol = colsum[col];
    unsigned fP0 = 0, fP1 = 0, fN0 = 0, fN1 = 0;
    float* ob = out + (size_t)(t + 1) * SLICE_T;
#pragma unroll
    for (int mt = 0; mt < 4; ++mt)
#pragma unroll
        for (int r = 0; r < 4; ++r) {
            const int row = mt * 16 + kg * 4 + r;
            const float v = acc[mt][0][r] + acc[mt][1][r] + acc[mt][2][r];
            ob[(size_t)row * HDIM + col] = v;
            const unsigned bit = 1u << (row & 31);
            if (v + cscol <= SAT_MARGIN)  { if (row < 32) fP0 |= bit; else fP1 |= bit; }
            if (v - cscol >= -SAT_MARGIN) { if (row < 32) fN0 |= bit; else fN1 |= bit; }
        }
#pragma unroll
    for (int off = 32; off; off >>= 1) {
        fP0 |= __shfl_xor(fP0, off); fP1 |= __shfl_xor(fP1, off);
        fN0 |= __shfl_xor(fN0, off); fN1 |= __shfl_xor(fN1, off);
    }
    if (lane == 0) {
        atomicOr(&sf[0], fP0); atomicOr(&sf[1], fP1);
        atomicOr(&sf[2], fN0); atomicOr(&sf[3], fN1);
    }
    __syncthreads();
    if (tid < 2) atomicAnd(&fpos32[t * 2 + tid], ~sf[tid]);
    else if (tid < 4) atomicAnd(&fneg32[t * 2 + (tid - 2)], ~sf[tid]);
}

// ------- Phase 2: persistent scan + per-row-sign sprint, 64-step batched --
// (proven R18/R22, byte-identical)
__global__ __launch_bounds__(128, 1) void rnn_scan(
    const float* __restrict__ weight, const float* __restrict__ init_h,
    const float* __restrict__ colsum, float* __restrict__ out,
    unsigned char* __restrict__ ws)
{
    __shared__ u32x4 whfA[16][2][64];
    __shared__ u32x4 whfB[16][2][64];
    unsigned* canary = (unsigned*)(ws + CAN_OFF);
    const u64* fpos = (const u64*)(ws + FPOS_OFF);
    const u64* fneg = (const u64*)(ws + FNEG_OFF);
    unsigned* ring = (unsigned*)(ws + RING_OFF);

    const int tid = threadIdx.x, lane = tid & 63, wv = tid >> 6;
    const int g = blockIdx.x & 7, s = blockIdx.x >> 3;
    const int r16 = lane & 15, kg = lane >> 4, koff = kg * 8;
    const int gcol = s * 32 + wv * 16 + r16;
    const int brow = g * 8 + (r16 & 7);

#pragma unroll
    for (int c = 0; c < 16; ++c) {
        unsigned p[8];
#pragma unroll
        for (int j = 0; j < 8; ++j)
            p[j] = packsplit(weight[(size_t)(HDIM + c * 32 + koff + j) * HDIM + gcol]);
        whfA[c][wv][lane] = (u32x4){p[0], p[1], p[2], p[3]};
        whfB[c][wv][lane] = (u32x4){p[4], p[5], p[6], p[7]};
    }
    for (int f = tid; f < 8 * 32; f += 128) {
        const int rr = f >> 5, cc = f & 31;
        out[(size_t)(g * 8 + rr) * HDIM + s * 32 + cc] = init_h[s * 32 + cc];
    }
    __syncthreads();

    int sprint = 0;
    unsigned smask = 0;   // bit b: row g*8+b is -1 (else +1); wave-uniform
    for (int t = 0; t < T_STEPS; ++t) {
        const bool has_next = (t + 1 < T_STEPS);

        if (sprint) {
            const unsigned pm = (~smask) & 0xFFu;
            if (t + 64 <= T_STEPS) {
                int pass = 1;
                {
                    const u64 fp = fpos[t + lane], fn = fneg[t + lane];
                    const unsigned fpg = (unsigned)((fp >> (g * 8)) & 0xFFull);
                    const unsigned fng = (unsigned)((fn >> (g * 8)) & 0xFFull);
                    pass = (((fpg & pm) == pm) && ((fng & smask) == smask)) ? 1 : 0;
                }
                if (__all(pass)) {
                    float* base = out + (size_t)(g * 8) * HDIM + s * 32;
#pragma unroll
                    for (int w = 0; w < 32; ++w) {
                        const int idx = w * 128 + tid;        // 0..4095
                        const int t2 = t + (idx >> 6);
                        const int v4i = idx & 63;
                        const int row = v4i >> 3, c4 = v4i & 7;
                        const float vv = ((smask >> row) & 1u) ? -1.0f : 1.0f;
                        const f32x4 vvec = {vv, vv, vv, vv};
                        __builtin_nontemporal_store(
                            vvec, (f32x4*)(base + (size_t)(t2 + 1) * SLICE_T
                                                + (size_t)row * HDIM + c4 * 4));
                    }
                    t += 63;
                    continue;
                }
            }
            const unsigned fpg = (unsigned)((fpos[t] >> (g * 8)) & 0xFFull);
            const unsigned fng = (unsigned)((fneg[t] >> (g * 8)) & 0xFFull);
            if (((fpg & pm) == pm) && ((fng & smask) == smask)) {
                float* ob = out + (size_t)(t + 1) * SLICE_T + (size_t)(g * 8) * HDIM + s * 32;
                for (int i = tid; i < 8 * 32; i += 128) {
                    const int r = i >> 5;
                    const float v = ((smask >> r) & 1u) ? -1.0f : 1.0f;
                    __builtin_nontemporal_store(v, ob + (size_t)r * HDIM + (i & 31));
                }
                continue;
            }
            const float* xpp = out + (size_t)(t + 1) * SLICE_T
                                   + (size_t)(g * 8 + (kg & 1) * 4) * HDIM + gcol;
            const float cs = colsum[gcol];
            float hn[4];
#pragma unroll
            for (int r = 0; r < 4; ++r) {
                const int rr = (kg & 1) * 4 + r;
                const float sg_ = ((smask >> rr) & 1u) ? -1.0f : 1.0f;
                hn[r] = fast_tanh(xpp[r * HDIM] + sg_ * cs);
            }
            if (kg < 2 && has_next) {
                unsigned* wsl = ring + ((t + 1) & 1) * SLICE_T
                                     + (size_t)(g * 8 + kg * 4) * HDIM + gcol;
#pragma unroll
                for (int r = 0; r < 4; ++r)
                    ASWAP(&wsl[r * HDIM], packsplit(hn[r]));
            }
            asm volatile("s_waitcnt vmcnt(0)" ::: "memory");
            __syncthreads();
            if (tid == 0 && has_next)
                ASWAP(&canary[(g * NSLICE + s) * 32], (unsigned)(t + 1));
            if (kg < 2) {
                float* op = out + (size_t)(t + 1) * SLICE_T
                                + (size_t)(g * 8 + kg * 4) * HDIM + gcol;
#pragma unroll
                for (int r = 0; r < 4; ++r)
                    __builtin_nontemporal_store(hn[r], op + (size_t)r * HDIM);
            }
            sprint = 0;
            continue;
        }

        const float* xpp = out + (size_t)(t + 1) * SLICE_T
                               + (size_t)(g * 8 + (kg & 1) * 4) * HDIM + gcol;
        const float xp0 = xpp[0 * HDIM], xp1 = xpp[1 * HDIM];
        const float xp2 = xpp[2 * HDIM], xp3 = xpp[3 * HDIM];

        f32x4 aA = {0, 0, 0, 0}, aB = {0, 0, 0, 0}, aC = {0, 0, 0, 0};

        if (t == 0) {
#pragma unroll
            for (int c = 0; c < 16; ++c) {
                f32x4 u = *(const f32x4*)(init_h + c * 32 + koff);
                f32x4 v = *(const f32x4*)(init_h + c * 32 + koff + 4);
                short8 ahi_, alo_; split8v(u, v, ahi_, alo_);
                short8 bhi, blo; build8v(whfA[c][wv][lane], whfB[c][wv][lane], bhi, blo);
                aA = MFMA16(ahi_, bhi, aA, 0, 0, 0);
                aB = MFMA16(alo_, bhi, aB, 0, 0, 0);
                aC = MFMA16(ahi_, blo, aC, 0, 0, 0);
            }
        } else {
            int to = 0;
            if (wv == 0) {
                unsigned it = 0;
                for (;;) {
                    unsigned cv = 0xffffffffu;
                    if (lane < NSLICE) cv = ALOAD(&canary[(g * NSLICE + lane) * 32]);
                    if (__all((int)(cv >= (unsigned)t))) break;
                    if (++it > SPIN_CAP) { to = 1; break; }
                }
            }
            if (__syncthreads_count(to)) return;

            const unsigned* rb = ring + (t & 1) * SLICE_T + brow * HDIM;
            unsigned long long q[16][4];
#pragma unroll
            for (int c = 0; c < 16; ++c) {
                const unsigned* p = rb + c * 32 + koff;
                q[c][0] = ALOAD((const unsigned long long*)(p + 0));
                q[c][1] = ALOAD((const unsigned long long*)(p + 2));
                q[c][2] = ALOAD((const unsigned long long*)(p + 4));
                q[c][3] = ALOAD((const unsigned long long*)(p + 6));
            }
            const unsigned long long P2 = 0x00003F8000003F80ull;  // +1,+1
            const unsigned long long N2 = 0x0000BF800000BF80ull;  // -1,-1
            unsigned long long dp = 0, dn = 0;
#pragma unroll
            for (int c = 0; c < 16; ++c) {
                dp |= (q[c][0] ^ P2) | (q[c][1] ^ P2) | (q[c][2] ^ P2) | (q[c][3] ^ P2);
                dn |= (q[c][0] ^ N2) | (q[c][1] ^ N2) | (q[c][2] ^ N2) | (q[c][3] ^ N2);
            }
            const unsigned code = (dp == 0ull) ? 0u : ((dn == 0ull) ? 1u : 2u);
            const unsigned long long balneg = __ballot((int)(code == 1u));
            const unsigned long long balbad = __ballot((int)(code == 2u));
            const unsigned my = (unsigned)((balneg >> (lane & 7)) & 1ull);
            const bool entry = (balbad == 0ull) && __all((int)(code == my));
            if (entry) {
                const unsigned sm = (unsigned)(balneg & 0xFFull);
                const unsigned fpg = (unsigned)((fpos[t] >> (g * 8)) & 0xFFull);
                const unsigned fng = (unsigned)((fneg[t] >> (g * 8)) & 0xFFull);
                const unsigned pm = (~sm) & 0xFFu;
                if (((fpg & pm) == pm) && ((fng & sm) == sm)) {
                    float* ob = out + (size_t)(t + 1) * SLICE_T + (size_t)(g * 8) * HDIM + s * 32;
                    for (int i = tid; i < 8 * 32; i += 128) {
                        const int r = i >> 5;
                        const float v = ((sm >> r) & 1u) ? -1.0f : 1.0f;
                        __builtin_nontemporal_store(v, ob + (size_t)r * HDIM + (i & 31));
                    }
                    sprint = 1; smask = sm;
                    continue;
                }
            }
#pragma unroll
            for (int c = 0; c < 16; ++c) {
                S8U hh, hl;
                unpack2w((unsigned)q[c][0], (unsigned)(q[c][0] >> 32), hh.u[0], hl.u[0]);
                unpack2w((unsigned)q[c][1], (unsigned)(q[c][1] >> 32), hh.u[1], hl.u[1]);
                unpack2w((unsigned)q[c][2], (unsigned)(q[c][2] >> 32), hh.u[2], hl.u[2]);
                unpack2w((unsigned)q[c][3], (unsigned)(q[c][3] >> 32), hh.u[3], hl.u[3]);
                short8 bhi, blo; build8v(whfA[c][wv][lane], whfB[c][wv][lane], bhi, blo);
                aA = MFMA16(hh.s8, bhi, aA, 0, 0, 0);
                aB = MFMA16(hl.s8, bhi, aB, 0, 0, 0);
                aC = MFMA16(hh.s8, blo, aC, 0, 0, 0);
            }
        }

        const float hn0 = fast_tanh(aA[0] + aB[0] + aC[0] + xp0);
        const float hn1 = fast_tanh(aA[1] + aB[1] + aC[1] + xp1);
        const float hn2 = fast_tanh(aA[2] + aB[2] + aC[2] + xp2);
        const float hn3 = fast_tanh(aA[3] + aB[3] + aC[3] + xp3);

        if (kg < 2 && has_next) {
            unsigned* wsl = ring + ((t + 1) & 1) * SLICE_T
                                 + (size_t)(g * 8 + kg * 4) * HDIM + gcol;
            ASWAP(&wsl[0 * HDIM], packsplit(hn0));
            ASWAP(&wsl[1 * HDIM], packsplit(hn1));
            ASWAP(&wsl[2 * HDIM], packsplit(hn2));
            ASWAP(&wsl[3 * HDIM], packsplit(hn3));
        }
        asm volatile("s_waitcnt vmcnt(0)" ::: "memory");
        __syncthreads();
        if (tid == 0 && has_next)
            ASWAP(&canary[(g * NSLICE + s) * 32], (unsigned)(t + 1));

        if (kg < 2) {
            float* op = out + (size_t)(t + 1) * SLICE_T
                            + (size_t)(g * 8 + kg * 4) * HDIM + gcol;
            __builtin_nontemporal_store(hn0, op + 0 * HDIM);
            __builtin_nontemporal_store(hn1, op + 1 * HDIM);
            __builtin_nontemporal_store(hn2, op + 2 * HDIM);
            __builtin_nontemporal_store(hn3, op + 3 * HDIM);
        }
    }
}

extern "C" void kernel_launch(void* const* d_in, const int* in_sizes, int n_in,
                              void* d_out, int out_size, void* d_ws, size_t ws_size,
                              hipStream_t stream) {
    const float* input  = (const float*)d_in[0];
    const float* weight = (const float*)d_in[1];
    const float* biasp  = (const float*)d_in[2];
    const float* inith  = (const float*)d_in[3];
    float* out = (float*)d_out;
    unsigned char* ws = (unsigned char*)d_ws;

    hipMemsetAsync(ws + CAN_OFF, 0, 16384, stream);
    hipMemsetAsync(ws + FPOS_OFF, 0xFF, 32768, stream);

    rnn_colsum<<<dim3(1), dim3(512), 0, stream>>>(weight, (float*)(ws + COLSUM_OFF));
    rnn_packw<<<dim3(256), dim3(512), 0, stream>>>(
        weight, (unsigned*)(ws + WHI_OFF), (unsigned*)(ws + WLO_OFF));
    rnn_xproj<<<dim3(T_STEPS * 4), dim3(512), 0, stream>>>(
        input, (const unsigned*)(ws + WHI_OFF), (const unsigned*)(ws + WLO_OFF),
        biasp, (const float*)(ws + COLSUM_OFF), out,
        (unsigned*)(ws + FPOS_OFF), (unsigned*)(ws + FNEG_OFF));
    rnn_scan<<<dim3(NGROUP * NSLICE), dim3(128), 0, stream>>>(
        weight, inith, (const float*)(ws + COLSUM_OFF), out, ws);
}